// Round 4
// baseline (1662.355 us; speedup 1.0000x reference)
//
#include <hip/hip_runtime.h>
#include <stdint.h>
#include <limits.h>

// ---------- exact-rounding helpers (block FMA contraction; match numpy op order) ----------
__device__ inline float mul_rn(float a, float b){ float r; asm("v_mul_f32 %0, %1, %2" : "=v"(r) : "v"(a), "v"(b)); return r; }
__device__ inline float add_rn(float a, float b){ float r; asm("v_add_f32 %0, %1, %2" : "=v"(r) : "v"(a), "v"(b)); return r; }
__device__ inline float sub_rn(float a, float b){ float r; asm("v_sub_f32 %0, %1, %2" : "=v"(r) : "v"(a), "v"(b)); return r; }

typedef uint16_t u16x8 __attribute__((ext_vector_type(8)));
typedef float    f32x2 __attribute__((ext_vector_type(2)));

// packed 2xf32 ops (VOP3P, IEEE RNE per element — bit-identical to scalar v_add/v_mul)
__device__ inline f32x2 pk_add2(f32x2 a, f32x2 b){ f32x2 r; asm("v_pk_add_f32 %0, %1, %2" : "=v"(r) : "v"(a), "v"(b)); return r; }
__device__ inline f32x2 pk_mul2(f32x2 a, f32x2 b){ f32x2 r; asm("v_pk_mul_f32 %0, %1, %2" : "=v"(r) : "v"(a), "v"(b)); return r; }

__device__ inline float bf2f(uint16_t u){ return __uint_as_float(((uint32_t)u) << 16); }
__device__ inline uint16_t f2bf(float f){
    uint32_t u = __float_as_uint(f);
    u += 0x7fffu + ((u >> 16) & 1u);   // RNE
    return (uint16_t)(u >> 16);
}
// monotonic uint key for float (total order): k(f) increasing in f
__device__ inline unsigned fkey(float f){
    unsigned u = __float_as_uint(f);
    return (u & 0x80000000u) ? ~u : (u | 0x80000000u);
}
__device__ inline float funkey(unsigned k){
    unsigned u = (k & 0x80000000u) ? (k ^ 0x80000000u) : ~k;
    return __uint_as_float(u);
}

// u64 {hi=value bits, lo=~idx} wave-max via DPP (row_shr 1/2/4/8 + row_bcast 15/31).
// max is idempotent -> no row/bank masks needed; bound_ctrl=false keeps old value on invalid lanes.
// Result: lane 63 holds the wave maximum.
__device__ inline void dppmax64(unsigned &lo, unsigned &hi){
#define DSTEP(C) { \
    unsigned nlo = (unsigned)__builtin_amdgcn_update_dpp((int)lo, (int)lo, C, 0xf, 0xf, false); \
    unsigned nhi = (unsigned)__builtin_amdgcn_update_dpp((int)hi, (int)hi, C, 0xf, 0xf, false); \
    unsigned long long a = (((unsigned long long)hi) << 32) | lo; \
    unsigned long long b = (((unsigned long long)nhi) << 32) | nlo; \
    if (b > a){ lo = nlo; hi = nhi; } }
    DSTEP(0x111) DSTEP(0x112) DSTEP(0x114) DSTEP(0x118) DSTEP(0x142) DSTEP(0x143)
#undef DSTEP
}

#define NPTS   8192
#define NBATCH 16
#define NPOINT 1024
#define NSAMP  32
#define LCOLS  32768          // NPOINT*NSAMP
#define NTOT   524288.0f      // 16*32768
#define NBUCK  32

// ---------- workspace layout (bytes) ----------
#define OFF_FPS   0u               // 16*1024*4 = 65536
#define OFF_GIDX  65536u           // 16*1024*32*4 = 2097152
#define OFF_SSC   2162688u         // 3 layers * 32 buckets * 256 f32 = 98304
#define OFF_PAR   2260992u         // 2 layers * 256 f32 = 2048
#define OFF_MM    2263040u         // mmax 2048 u32 ; mmin 2048 u32 = 16384
#define OFF_WT    2279424u         // 66304
#define OFF_T0    4194304u         // 67108864
#define OFF_T1    71303168u        // 67108864
#define OFF_PTST  138412032u       // 16777216 (end 155189248)

// ---------- 1) FUSED: fps (blocks 0..15) + pts transpose (16..527) + weight prep (528..535) ----------
// Paths are fully independent (no cross-path data deps) -> safe under any dispatch order.
// 96KB LDS => 1 block/CU: the 16 fps blocks own their CUs; transpose/prep fill the other 240
// CUs and finish well inside fps's runtime.
__global__ __launch_bounds__(1024) void fps_fused_kernel(const float* __restrict__ xyz,
        int* __restrict__ fps_idx, float* __restrict__ out_xyz,
        const float* __restrict__ pts, uint16_t* __restrict__ ptsT,
        const float* __restrict__ w0, const float* __restrict__ w1, const float* __restrict__ w2,
        float* __restrict__ wt0, float* __restrict__ wt1, float* __restrict__ wt2){
    __shared__ __align__(16) float smem[24584];
    const int bid = blockIdx.x, tid = threadIdx.x;

    if (bid >= 528){                       // ---- prep path: wt[c][o] transposes ----
        int t = (bid - 528) * 1024 + tid;  // 0..8191
        if (t < 64*67){ int o = t / 67, c = t % 67; wt0[c*64 + o] = w0[t]; }
        if (t < 64*64){ int o = t >> 6, c = t & 63; wt1[c*64 + o] = w1[t]; }
        if (t < 128*64){ int o = t >> 6, c = t & 63; wt2[c*128 + o] = w2[t]; }
        return;
    }
    if (bid >= 16){                        // ---- transpose path: (B,64,N)f32 -> (B,N,64)bf16 ----
        float (*tile)[261] = (float(*)[261])smem;
        const int tb = bid - 16;
        const int bt = tb >> 5, n0 = (tb & 31) << 8;        // 256 n-cols per block
        const int tn = tid & 255, tg = tid >> 8;            // tg 0..3
        const float* src = pts + (size_t)bt * 64 * NPTS + n0;
#pragma unroll
        for (int i = 0; i < 16; i++){ int c = tg*16 + i; tile[c][tn] = src[(size_t)c * NPTS + tn]; }
        __syncthreads();
        const int n = tid >> 2, cc = tid & 3;               // 4 threads per n, 16 c each
        uint16_t* dst = ptsT + ((size_t)bt * NPTS + n0 + n) * 64 + cc * 16;
        u16x8 a, b2;
#pragma unroll
        for (int i = 0; i < 8; i++)  a[i]  = f2bf(tile[cc*16 + i][n]);
#pragma unroll
        for (int i = 0; i < 8; i++)  b2[i] = f2bf(tile[cc*16 + 8 + i][n]);
        *(u16x8*)dst = a;
        *(u16x8*)(dst + 8) = b2;
        return;
    }

    // ---- fps path: one block per batch; contiguous ownership p = tid*8+j ----
    float* sx = smem; float* sy = smem + 8192; float* sz = smem + 16384;
    unsigned long long* slot = (unsigned long long*)(smem + 24576);   // 3 rotating slots
    const int b = bid;
    const float* px = xyz + (size_t)b * 3 * NPTS;
    for (int i = tid; i < NPTS; i += 1024){ sx[i] = px[i]; sy[i] = px[NPTS+i]; sz[i] = px[2*NPTS+i]; }
    if (tid < 3) slot[tid] = 0ull;
    __syncthreads();

    f32x2 X2[4], Y2[4], Z2[4], M2[4];
    unsigned nb[8];
    const int p0 = tid << 3;
#pragma unroll
    for (int j = 0; j < 4; j++){
        X2[j] = *(const f32x2*)(sx + p0 + 2*j);
        Y2[j] = *(const f32x2*)(sy + p0 + 2*j);
        Z2[j] = *(const f32x2*)(sz + p0 + 2*j);
        M2[j] = f32x2{1e10f, 1e10f};
    }
#pragma unroll
    for (int k = 0; k < 8; k++) nb[k] = ~(unsigned)(p0 + k);

    int cur = 0, r = 0;
    int* fout = fps_idx + b * NPOINT;
    float* oxp = out_xyz + b * 3 * NPOINT;
    for (int t = 0; t < NPOINT; t++){
        const float cx = sx[cur], cy = sy[cur], cz = sz[cur];
        if (tid == 0){ fout[t] = cur; oxp[t] = cx; oxp[NPOINT+t] = cy; oxp[2*NPOINT+t] = cz; }
        const f32x2 ncx = f32x2{-cx, -cx}, ncy = f32x2{-cy, -cy}, ncz = f32x2{-cz, -cz};
#pragma unroll
        for (int j = 0; j < 4; j++){
            f32x2 dx = pk_add2(X2[j], ncx);
            f32x2 dy = pk_add2(Y2[j], ncy);
            f32x2 dz = pk_add2(Z2[j], ncz);
            f32x2 d2 = pk_add2(pk_add2(pk_mul2(dx,dx), pk_mul2(dy,dy)), pk_mul2(dz,dz));
            M2[j].x = fminf(M2[j].x, d2.x);
            M2[j].y = fminf(M2[j].y, d2.y);
        }
        float t1 = fmaxf(fmaxf(M2[0].x, M2[0].y), fmaxf(M2[1].x, M2[1].y));
        float t2 = fmaxf(fmaxf(M2[2].x, M2[2].y), fmaxf(M2[3].x, M2[3].y));
        float mt = fmaxf(t1, t2);
        // smallest owned index with M==mt (descending scan -> smallest j wins)
        unsigned lo = 0;
#pragma unroll
        for (int j = 3; j >= 0; j--){
            if (M2[j].y == mt) lo = nb[2*j + 1];
            if (M2[j].x == mt) lo = nb[2*j];
        }
        unsigned hi = __float_as_uint(mt);      // d2 >= 0 -> uint order == float order
        dppmax64(lo, hi);                       // lane 63 <- wave max (value, ~idx)
        if ((tid & 63) == 63)
            atomicMax(&slot[r], (((unsigned long long)hi) << 32) | lo);
        int rn = r + 1; if (rn == 3) rn = 0;
        if (tid == 0) slot[rn] = 0ull;          // last read of slot[rn] was 2 barriers ago: safe
        __syncthreads();
        cur = (int)(~((unsigned)slot[r]));
        r = rn;
    }
}

// ---------- 2) ball query: one wave per (b,s) ----------
__global__ __launch_bounds__(256) void ballquery_kernel(const float* __restrict__ xyz,
                                                        const int* __restrict__ fps_idx, int* __restrict__ gidx){
    const int w = (blockIdx.x << 2) + (threadIdx.x >> 6);
    const int lane = threadIdx.x & 63;
    const int b = w >> 10, s = w & 1023;
    const float* px = xyz + (size_t)b * 3 * NPTS;
    const int ci = fps_idx[b * NPOINT + s];
    const float cx = px[ci], cy = px[NPTS+ci], cz = px[2*NPTS+ci];
    int* gout = gidx + (size_t)b * LCOLS + s * NSAMP;
    int have = 0, first_p = 0; bool got = false;
    for (int c0 = 0; c0 < NPTS; c0 += 64){
        int p = c0 + lane;
        float dx = sub_rn(px[p], cx), dy = sub_rn(px[NPTS+p], cy), dz = sub_rn(px[2*NPTS+p], cz);
        float d2 = add_rn(add_rn(mul_rn(dx,dx), mul_rn(dy,dy)), mul_rn(dz,dz));
        bool in = (d2 <= 0.01f);
        unsigned long long m = __ballot(in);
        if (m && !got){ first_p = c0 + __ffsll(m) - 1; got = true; }
        if (in){
            int pos = have + __popcll(m & ((1ull << lane) - 1ull));
            if (pos < NSAMP) gout[pos] = p;
        }
        have += __popcll(m);
        if (have >= NSAMP) break;
    }
    for (int pos = have + lane; pos < NSAMP; pos += 64) gout[pos] = first_p;
}

// ---------- 3) fused conv+BN-stats kernel ----------
template<int CIN, int COUT, bool ACT, bool GATHER, bool WRITE, bool MAXMIN>
__global__ __launch_bounds__(256) void mm_kernel(const uint16_t* __restrict__ xin,
        const float* __restrict__ xyz, const float* __restrict__ nx,
        const uint16_t* __restrict__ ptsT, const int* __restrict__ gidx,
        const float* __restrict__ wt, const float* __restrict__ bias, const float* __restrict__ ac,
        uint16_t* __restrict__ xout, float* __restrict__ ssc,
        unsigned* __restrict__ mmax, unsigned* __restrict__ mmin){
    __shared__ __align__(16) float sw[CIN * COUT];
    __shared__ float sb[COUT];
    __shared__ float sa[ACT ? 2*CIN : 1];
    __shared__ __align__(16) float sred[16 * 260];
    const int tid = threadIdx.x;
    for (int i = tid; i < CIN * COUT; i += 256) sw[i] = wt[i];
    if (tid < COUT) sb[tid] = bias[tid];
    if constexpr (ACT){ if (tid < CIN){ sa[tid] = ac[tid]; sa[CIN + tid] = ac[128 + tid]; } }
    __syncthreads();
    const int b = blockIdx.x >> 7;
    const int ls = ((blockIdx.x & 127) << 8) + tid;
    float f[CIN];
    if constexpr (GATHER){
        const int s = ls >> 5;
        const int g = gidx[(size_t)b * LCOLS + ls];
        const float* px = xyz + (size_t)b * 3 * NPTS;
        const float cx = nx[b*3*NPOINT + s], cy = nx[b*3*NPOINT + NPOINT + s], cz = nx[b*3*NPOINT + 2*NPOINT + s];
        f[0] = sub_rn(px[g], cx); f[1] = sub_rn(px[NPTS+g], cy); f[2] = sub_rn(px[2*NPTS+g], cz);
        const u16x8* pr = (const u16x8*)(ptsT + ((size_t)b * NPTS + (size_t)g) * 64);
#pragma unroll
        for (int jj = 0; jj < 8; jj++){
            u16x8 v = pr[jj];
#pragma unroll
            for (int e = 0; e < 8; e++) f[3 + jj*8 + e] = bf2f(v[e]);
        }
    } else {
        const uint16_t* xp = xin + (size_t)b * CIN * LCOLS + ls;
#pragma unroll
        for (int c = 0; c < CIN; c++){
            float v = bf2f(xp[(size_t)c * LCOLS]);
            if constexpr (ACT) v = fmaxf(fmaf(sa[c], v, sa[CIN + c]), 0.0f);
            f[c] = v;
        }
    }
    uint16_t* op = xout + (size_t)b * COUT * LCOLS + ls;
    float* sbck = ssc + (blockIdx.x & (NBUCK-1)) * 256;
    for (int o0 = 0; o0 < COUT; o0 += 16){
        float acc[16];
#pragma unroll
        for (int j = 0; j < 16; j++) acc[j] = sb[o0 + j];
#pragma unroll
        for (int c = 0; c < CIN; c++){
            const float4* wr = (const float4*)(sw + c * COUT + o0);  // uniform -> LDS broadcast
            float4 w0_ = wr[0], w1_ = wr[1], w2_ = wr[2], w3_ = wr[3];
            const float fc = f[c];
            acc[0]  = fmaf(w0_.x, fc, acc[0]);  acc[1]  = fmaf(w0_.y, fc, acc[1]);
            acc[2]  = fmaf(w0_.z, fc, acc[2]);  acc[3]  = fmaf(w0_.w, fc, acc[3]);
            acc[4]  = fmaf(w1_.x, fc, acc[4]);  acc[5]  = fmaf(w1_.y, fc, acc[5]);
            acc[6]  = fmaf(w1_.z, fc, acc[6]);  acc[7]  = fmaf(w1_.w, fc, acc[7]);
            acc[8]  = fmaf(w2_.x, fc, acc[8]);  acc[9]  = fmaf(w2_.y, fc, acc[9]);
            acc[10] = fmaf(w2_.z, fc, acc[10]); acc[11] = fmaf(w2_.w, fc, acc[11]);
            acc[12] = fmaf(w3_.x, fc, acc[12]); acc[13] = fmaf(w3_.y, fc, acc[13]);
            acc[14] = fmaf(w3_.z, fc, acc[14]); acc[15] = fmaf(w3_.w, fc, acc[15]);
        }
        if constexpr (WRITE){
#pragma unroll
            for (int j = 0; j < 16; j++) op[(size_t)(o0 + j) * LCOLS] = f2bf(acc[j]);
        }
        // ---- block-level stats reduce on f32 accs ----
        __syncthreads();                       // protect sred reuse from previous group
#pragma unroll
        for (int k = 0; k < 16; k++) sred[k * 260 + tid] = acc[k];
        __syncthreads();
        const int ch = tid >> 4, seg = tid & 15;    // 16 ch x 16 segments of 16 cols
        float s = 0.f, ss = 0.f, mx = -1e30f, mn = 1e30f;
        const float4* rp = (const float4*)(sred + ch * 260 + seg * 16);
#pragma unroll
        for (int e = 0; e < 4; e++){
            float4 v = rp[e];
            s += v.x + v.y + v.z + v.w;
            ss = fmaf(v.x, v.x, ss); ss = fmaf(v.y, v.y, ss);
            ss = fmaf(v.z, v.z, ss); ss = fmaf(v.w, v.w, ss);
            if constexpr (MAXMIN){
                mx = fmaxf(mx, fmaxf(fmaxf(v.x, v.y), fmaxf(v.z, v.w)));
                mn = fminf(mn, fminf(fminf(v.x, v.y), fminf(v.z, v.w)));
            }
        }
        // 16 segs of one ch sit in consecutive lanes of one wave
#pragma unroll
        for (int off = 1; off < 16; off <<= 1){
            s += __shfl_xor(s, off); ss += __shfl_xor(ss, off);
            if constexpr (MAXMIN){ mx = fmaxf(mx, __shfl_xor(mx, off)); mn = fminf(mn, __shfl_xor(mn, off)); }
        }
        if (seg == 0){
            atomicAdd(&sbck[o0 + ch], s);
            atomicAdd(&sbck[128 + o0 + ch], ss);
            if constexpr (MAXMIN){
                atomicMax(&mmax[b * 128 + o0 + ch], fkey(mx));
                atomicMin(&mmin[b * 128 + o0 + ch], fkey(mn));
            }
        }
    }
}

// ---------- 4) BN params from bucketed sums -> per-channel affine a,c ----------
__global__ void params_kernel(const float* __restrict__ ssc, const float* __restrict__ g,
                              const float* __restrict__ beta, float* __restrict__ ac, int C){
    int o = threadIdx.x;
    if (o < C){
        float s = 0.f, ss = 0.f;
        for (int k = 0; k < NBUCK; k++){ s += ssc[k*256 + o]; ss += ssc[k*256 + 128 + o]; }
        const float inv = 1.0f / NTOT;
        float mean = s * inv;
        float var  = ss * inv - mean * mean;
        float a = g[o] / sqrtf(var + 1e-5f);
        ac[o] = a;
        ac[128 + o] = fmaf(-mean, a, beta[o]);
    }
}

// ---------- 5) finalize: out = relu(a * (a>=0 ? max : min) + c) per (b,ch) ----------
__global__ __launch_bounds__(64) void final_kernel(const float* __restrict__ ssc, const float* __restrict__ g2,
                                                   const float* __restrict__ be2, const unsigned* __restrict__ mmax,
                                                   const unsigned* __restrict__ mmin, float* __restrict__ out){
    const int t = blockIdx.x * 64 + threadIdx.x;   // 0..2047 : b*128+o
    const int o = t & 127;
    float s = 0.f, ss = 0.f;
    for (int k = 0; k < NBUCK; k++){ s += ssc[k*256 + o]; ss += ssc[k*256 + 128 + o]; }
    const float inv = 1.0f / NTOT;
    float mean = s * inv;
    float var  = ss * inv - mean * mean;
    float a = g2[o] / sqrtf(var + 1e-5f);
    float c = fmaf(-mean, a, be2[o]);
    unsigned k = (a >= 0.f) ? mmax[t] : mmin[t];   // relu(a*x+c) monotone in x, direction sign(a)
    float x = funkey(k);
    out[49152 + t] = fmaxf(fmaf(a, x, c), 0.0f);
}

extern "C" void kernel_launch(void* const* d_in, const int* in_sizes, int n_in,
                              void* d_out, int out_size, void* d_ws, size_t ws_size,
                              hipStream_t stream){
    const float* xyz = (const float*)d_in[0];
    const float* pts = (const float*)d_in[1];
    const float* w0  = (const float*)d_in[2];  const float* b0  = (const float*)d_in[3];
    const float* g0  = (const float*)d_in[4];  const float* be0 = (const float*)d_in[5];
    const float* w1  = (const float*)d_in[6];  const float* b1  = (const float*)d_in[7];
    const float* g1  = (const float*)d_in[8];  const float* be1 = (const float*)d_in[9];
    const float* w2  = (const float*)d_in[10]; const float* b2  = (const float*)d_in[11];
    const float* g2  = (const float*)d_in[12]; const float* be2 = (const float*)d_in[13];
    float* out = (float*)d_out;
    char* ws = (char*)d_ws;

    int*      fps_idx = (int*)(ws + OFF_FPS);
    int*      gidx    = (int*)(ws + OFF_GIDX);
    float*    ssc0    = (float*)(ws + OFF_SSC);            // 32*256
    float*    ssc1    = ssc0 + NBUCK*256;
    float*    ssc2    = ssc1 + NBUCK*256;
    float*    par0    = (float*)(ws + OFF_PAR);
    float*    par1    = par0 + 256;
    unsigned* mmax    = (unsigned*)(ws + OFF_MM);
    unsigned* mmin    = mmax + 2048;
    float*    wt0     = (float*)(ws + OFF_WT);
    float*    wt1     = wt0 + 67*64;
    float*    wt2     = wt1 + 64*64;
    uint16_t* t0      = (uint16_t*)(ws + OFF_T0);
    uint16_t* t1      = (uint16_t*)(ws + OFF_T1);
    uint16_t* ptsT    = (uint16_t*)(ws + OFF_PTST);

    hipMemsetAsync(ws + OFF_SSC, 0, 3 * NBUCK * 256 * 4, stream);
    hipMemsetAsync(ws + OFF_MM, 0x00, 8192, stream);          // key 0 < key(-inf)
    hipMemsetAsync(ws + OFF_MM + 8192, 0xFF, 8192, stream);   // key ~0 > key(+inf)

    fps_fused_kernel<<<536, 1024, 0, stream>>>(xyz, fps_idx, out, pts, ptsT,
                                               w0, w1, w2, wt0, wt1, wt2);
    ballquery_kernel<<<4096, 256, 0, stream>>>(xyz, fps_idx, gidx);

    mm_kernel<67, 64, false, true, true, false><<<2048, 256, 0, stream>>>(
        nullptr, xyz, out, ptsT, gidx, wt0, b0, nullptr, t0, ssc0, nullptr, nullptr);
    params_kernel<<<1, 128, 0, stream>>>(ssc0, g0, be0, par0, 64);

    mm_kernel<64, 64, true, false, true, false><<<2048, 256, 0, stream>>>(
        t0, nullptr, nullptr, nullptr, nullptr, wt1, b1, par0, t1, ssc1, nullptr, nullptr);
    params_kernel<<<1, 128, 0, stream>>>(ssc1, g1, be1, par1, 64);

    mm_kernel<64, 128, true, false, false, true><<<2048, 256, 0, stream>>>(
        t1, nullptr, nullptr, nullptr, nullptr, wt2, b2, par1, nullptr, ssc2, mmax, mmin);
    final_kernel<<<32, 64, 0, stream>>>(ssc2, g2, be2, mmax, mmin, out);
}

// Round 7
// 1548.745 us; speedup vs baseline: 1.0734x; 1.0734x over previous
//
#include <hip/hip_runtime.h>
#include <stdint.h>
#include <limits.h>

// ---------- exact-rounding helpers (block FMA contraction; match numpy op order) ----------
__device__ inline float mul_rn(float a, float b){ float r; asm("v_mul_f32 %0, %1, %2" : "=v"(r) : "v"(a), "v"(b)); return r; }
__device__ inline float add_rn(float a, float b){ float r; asm("v_add_f32 %0, %1, %2" : "=v"(r) : "v"(a), "v"(b)); return r; }
__device__ inline float sub_rn(float a, float b){ float r; asm("v_sub_f32 %0, %1, %2" : "=v"(r) : "v"(a), "v"(b)); return r; }

typedef uint16_t u16x8 __attribute__((ext_vector_type(8)));
typedef float    f32x2 __attribute__((ext_vector_type(2)));

// packed 2xf32 ops (VOP3P, IEEE RNE per element — bit-identical to scalar v_add/v_mul)
__device__ inline f32x2 pk_add2(f32x2 a, f32x2 b){ f32x2 r; asm("v_pk_add_f32 %0, %1, %2" : "=v"(r) : "v"(a), "v"(b)); return r; }
__device__ inline f32x2 pk_mul2(f32x2 a, f32x2 b){ f32x2 r; asm("v_pk_mul_f32 %0, %1, %2" : "=v"(r) : "v"(a), "v"(b)); return r; }

__device__ inline float bf2f(uint16_t u){ return __uint_as_float(((uint32_t)u) << 16); }
__device__ inline uint16_t f2bf(float f){
    uint32_t u = __float_as_uint(f);
    u += 0x7fffu + ((u >> 16) & 1u);   // RNE
    return (uint16_t)(u >> 16);
}
// monotonic uint key for float (total order): k(f) increasing in f
__device__ inline unsigned fkey(float f){
    unsigned u = __float_as_uint(f);
    return (u & 0x80000000u) ? ~u : (u | 0x80000000u);
}
__device__ inline float funkey(unsigned k){
    unsigned u = (k & 0x80000000u) ? (k ^ 0x80000000u) : ~k;
    return __uint_as_float(u);
}

// full-wave u32 max via DPP using the BUILTIN (compiler inserts the mandatory
// VALU->DPP hazard wait-states; raw back-to-back asm DPP reads stale VGPRs).
// Result valid in lane 63.
__device__ inline unsigned dpp_umax_wave(unsigned v){
    unsigned t;
    t = (unsigned)__builtin_amdgcn_update_dpp((int)v, (int)v, 0x111, 0xf, 0xf, false); v = v > t ? v : t; // row_shr:1
    t = (unsigned)__builtin_amdgcn_update_dpp((int)v, (int)v, 0x112, 0xf, 0xf, false); v = v > t ? v : t; // row_shr:2
    t = (unsigned)__builtin_amdgcn_update_dpp((int)v, (int)v, 0x114, 0xf, 0xf, false); v = v > t ? v : t; // row_shr:4
    t = (unsigned)__builtin_amdgcn_update_dpp((int)v, (int)v, 0x118, 0xf, 0xf, false); v = v > t ? v : t; // row_shr:8
    t = (unsigned)__builtin_amdgcn_update_dpp((int)v, (int)v, 0x142, 0xf, 0xf, false); v = v > t ? v : t; // row_bcast:15
    t = (unsigned)__builtin_amdgcn_update_dpp((int)v, (int)v, 0x143, 0xf, 0xf, false); v = v > t ? v : t; // row_bcast:31
    return v;
}

#define NPTS   8192
#define NBATCH 16
#define NPOINT 1024
#define NSAMP  32
#define LCOLS  32768          // NPOINT*NSAMP
#define NTOT   524288.0f      // 16*32768
#define NBUCK  32

// ---------- workspace layout (bytes) ----------
#define OFF_FPS   0u               // 16*1024*4 = 65536
#define OFF_GIDX  65536u           // 16*1024*32*4 = 2097152
#define OFF_SSC   2162688u         // 3 layers * 32 buckets * 256 f32 = 98304
#define OFF_PAR   2260992u         // 2 layers * 256 f32 = 2048
#define OFF_MM    2263040u         // mmax 2048 u32 ; mmin 2048 u32 = 16384
#define OFF_WT    2279424u         // 66304
#define OFF_T0    4194304u         // 67108864
#define OFF_T1    71303168u        // 67108864
#define OFF_PTST  138412032u       // 16777216 (end 155189248)

// ---------- 1) FUSED: fps (blocks 0..15) + pts transpose (16..527) + weight prep (528..535) ----------
__global__ __launch_bounds__(1024) void fps_fused_kernel(const float* __restrict__ xyz,
        int* __restrict__ fps_idx, float* __restrict__ out_xyz,
        const float* __restrict__ pts, uint16_t* __restrict__ ptsT,
        const float* __restrict__ w0, const float* __restrict__ w1, const float* __restrict__ w2,
        float* __restrict__ wt0, float* __restrict__ wt1, float* __restrict__ wt2){
    __shared__ __align__(16) float smem[24640];   // sxyz (8192*3) + wslots (2*16 u64)
    const int bid = blockIdx.x, tid = threadIdx.x;

    if (bid >= 528){                       // ---- prep path: wt[c][o] transposes ----
        int t = (bid - 528) * 1024 + tid;  // 0..8191
        if (t < 64*67){ int o = t / 67, c = t % 67; wt0[c*64 + o] = w0[t]; }
        if (t < 64*64){ int o = t >> 6, c = t & 63; wt1[c*64 + o] = w1[t]; }
        if (t < 128*64){ int o = t >> 6, c = t & 63; wt2[c*128 + o] = w2[t]; }
        return;
    }
    if (bid >= 16){                        // ---- transpose path: (B,64,N)f32 -> (B,N,64)bf16 ----
        float (*tile)[261] = (float(*)[261])smem;
        const int tb = bid - 16;
        const int bt = tb >> 5, n0 = (tb & 31) << 8;        // 256 n-cols per block
        const int tn = tid & 255, tg = tid >> 8;            // tg 0..3
        const float* src = pts + (size_t)bt * 64 * NPTS + n0;
#pragma unroll
        for (int i = 0; i < 16; i++){ int c = tg*16 + i; tile[c][tn] = src[(size_t)c * NPTS + tn]; }
        __syncthreads();
        const int n = tid >> 2, cc = tid & 3;               // 4 threads per n, 16 c each
        uint16_t* dst = ptsT + ((size_t)bt * NPTS + n0 + n) * 64 + cc * 16;
        u16x8 a, b2;
#pragma unroll
        for (int i = 0; i < 8; i++)  a[i]  = f2bf(tile[cc*16 + i][n]);
#pragma unroll
        for (int i = 0; i < 8; i++)  b2[i] = f2bf(tile[cc*16 + 8 + i][n]);
        *(u16x8*)dst = a;
        *(u16x8*)(dst + 8) = b2;
        return;
    }

    // ---- fps path: one block per batch; NO global stores / NO LDS atomics in the loop ----
    float* sxyz = smem;                                       // [8192*3] interleaved x,y,z
    unsigned long long* wslots = (unsigned long long*)(smem + 24576);  // flat [2*16]
    const int b = bid;
    const float* px = xyz + (size_t)b * 3 * NPTS;
    for (int i = tid; i < NPTS; i += 1024){
        sxyz[3*i]   = px[i];
        sxyz[3*i+1] = px[NPTS+i];
        sxyz[3*i+2] = px[2*NPTS+i];
    }
    __syncthreads();

    // per-thread 8 contiguous points p0..p0+7 from interleaved LDS (6 x b128)
    const int p0 = tid << 3;
    const float4* rp = (const float4*)(sxyz + 3*p0);
    float4 r0 = rp[0], r1 = rp[1], r2 = rp[2], r3 = rp[3], r4 = rp[4], r5 = rp[5];
    f32x2 X2[4], Y2[4], Z2[4], M2[4];
    X2[0] = f32x2{r0.x, r0.w}; Y2[0] = f32x2{r0.y, r1.x}; Z2[0] = f32x2{r0.z, r1.y};
    X2[1] = f32x2{r1.z, r2.y}; Y2[1] = f32x2{r1.w, r2.z}; Z2[1] = f32x2{r2.x, r2.w};
    X2[2] = f32x2{r3.x, r3.w}; Y2[2] = f32x2{r3.y, r4.x}; Z2[2] = f32x2{r3.z, r4.y};
    X2[3] = f32x2{r4.z, r5.y}; Y2[3] = f32x2{r4.w, r5.z}; Z2[3] = f32x2{r5.x, r5.w};
#pragma unroll
    for (int j = 0; j < 4; j++) M2[j] = f32x2{1e10f, 1e10f};
    unsigned nb[8];
#pragma unroll
    for (int k = 0; k < 8; k++) nb[k] = ~(unsigned)(p0 + k);

    int cur = 0, mycur = 0;
    float cx = sxyz[0], cy = sxyz[1], cz = sxyz[2];
    for (int t = 0; t < NPOINT; t++){
        if (tid == t) mycur = cur;                 // record s_t; one thread per iter
        const f32x2 ncx = f32x2{-cx, -cx}, ncy = f32x2{-cy, -cy}, ncz = f32x2{-cz, -cz};
#pragma unroll
        for (int j = 0; j < 4; j++){
            f32x2 dx = pk_add2(X2[j], ncx);
            f32x2 dy = pk_add2(Y2[j], ncy);
            f32x2 dz = pk_add2(Z2[j], ncz);
            f32x2 d2 = pk_add2(pk_add2(pk_mul2(dx,dx), pk_mul2(dy,dy)), pk_mul2(dz,dz));
            M2[j].x = fminf(M2[j].x, d2.x);
            M2[j].y = fminf(M2[j].y, d2.y);
        }
        float ta = fmaxf(fmaxf(M2[0].x, M2[0].y), fmaxf(M2[1].x, M2[1].y));
        float tb2 = fmaxf(fmaxf(M2[2].x, M2[2].y), fmaxf(M2[3].x, M2[3].y));
        float mt = fmaxf(ta, tb2);
        // smallest owned index with M==mt (descending scan -> smallest j wins)
        unsigned lo = 0;
#pragma unroll
        for (int j = 3; j >= 0; j--){
            if (M2[j].y == mt) lo = nb[2*j + 1];
            if (M2[j].x == mt) lo = nb[2*j];
        }
        const unsigned mtu = __float_as_uint(mt);       // d2>=0 -> uint order == float order
        unsigned vm = dpp_umax_wave(mtu);
        const unsigned wvu = __builtin_amdgcn_readlane(vm, 63);
        unsigned long long cand = __ballot(mtu == wvu);
        const int fl = __ffsll((long long)cand) - 1;    // lowest lane = smallest p among ties
        const unsigned wlo = __builtin_amdgcn_readlane(lo, fl);
        if ((tid & 63) == 63)
            wslots[(t & 1) * 16 + (tid >> 6)] = (((unsigned long long)wvu) << 32) | wlo;
        __syncthreads();                                // the ONLY barrier per iter
        unsigned long long k = wslots[(t & 1) * 16 + (tid & 15)];
        unsigned klo = (unsigned)k, khi = (unsigned)(k >> 32);
#define ST(C) { unsigned nlo = (unsigned)__builtin_amdgcn_update_dpp((int)klo, (int)klo, C, 0xf, 0xf, false); \
                unsigned nhi = (unsigned)__builtin_amdgcn_update_dpp((int)khi, (int)khi, C, 0xf, 0xf, false); \
                unsigned long long ko = (((unsigned long long)khi) << 32) | klo; \
                unsigned long long kn = (((unsigned long long)nhi) << 32) | nlo; \
                if (kn > ko){ klo = nlo; khi = nhi; } }
        ST(0x111) ST(0x112) ST(0x114) ST(0x118)         // row_shr 1,2,4,8 -> lane15 of each row
#undef ST
        cur = (int)(~__builtin_amdgcn_readlane(klo, 15));
        cx = sxyz[3*cur]; cy = sxyz[3*cur+1]; cz = sxyz[3*cur+2];
    }
    // single output phase
    fps_idx[b * NPOINT + tid] = mycur;
    float* oxp = out_xyz + b * 3 * NPOINT;
    oxp[tid]            = sxyz[3*mycur];
    oxp[NPOINT + tid]   = sxyz[3*mycur+1];
    oxp[2*NPOINT + tid] = sxyz[3*mycur+2];
}

// ---------- 2) ball query: one wave per (b,s) ----------
__global__ __launch_bounds__(256) void ballquery_kernel(const float* __restrict__ xyz,
                                                        const int* __restrict__ fps_idx, int* __restrict__ gidx){
    const int w = (blockIdx.x << 2) + (threadIdx.x >> 6);
    const int lane = threadIdx.x & 63;
    const int b = w >> 10, s = w & 1023;
    const float* px = xyz + (size_t)b * 3 * NPTS;
    const int ci = fps_idx[b * NPOINT + s];
    const float cx = px[ci], cy = px[NPTS+ci], cz = px[2*NPTS+ci];
    int* gout = gidx + (size_t)b * LCOLS + s * NSAMP;
    int have = 0, first_p = 0; bool got = false;
    for (int c0 = 0; c0 < NPTS; c0 += 64){
        int p = c0 + lane;
        float dx = sub_rn(px[p], cx), dy = sub_rn(px[NPTS+p], cy), dz = sub_rn(px[2*NPTS+p], cz);
        float d2 = add_rn(add_rn(mul_rn(dx,dx), mul_rn(dy,dy)), mul_rn(dz,dz));
        bool in = (d2 <= 0.01f);
        unsigned long long m = __ballot(in);
        if (m && !got){ first_p = c0 + __ffsll(m) - 1; got = true; }
        if (in){
            int pos = have + __popcll(m & ((1ull << lane) - 1ull));
            if (pos < NSAMP) gout[pos] = p;
        }
        have += __popcll(m);
        if (have >= NSAMP) break;
    }
    for (int pos = have + lane; pos < NSAMP; pos += 64) gout[pos] = first_p;
}

// ---------- 3) fused conv+BN-stats kernel ----------
template<int CIN, int COUT, bool ACT, bool GATHER, bool WRITE, bool MAXMIN>
__global__ __launch_bounds__(256) void mm_kernel(const uint16_t* __restrict__ xin,
        const float* __restrict__ xyz, const float* __restrict__ nx,
        const uint16_t* __restrict__ ptsT, const int* __restrict__ gidx,
        const float* __restrict__ wt, const float* __restrict__ bias, const float* __restrict__ ac,
        uint16_t* __restrict__ xout, float* __restrict__ ssc,
        unsigned* __restrict__ mmax, unsigned* __restrict__ mmin){
    __shared__ __align__(16) float sw[CIN * COUT];
    __shared__ float sb[COUT];
    __shared__ float sa[ACT ? 2*CIN : 1];
    __shared__ __align__(16) float sred[16 * 260];
    const int tid = threadIdx.x;
    for (int i = tid; i < CIN * COUT; i += 256) sw[i] = wt[i];
    if (tid < COUT) sb[tid] = bias[tid];
    if constexpr (ACT){ if (tid < CIN){ sa[tid] = ac[tid]; sa[CIN + tid] = ac[128 + tid]; } }
    __syncthreads();
    const int b = blockIdx.x >> 7;
    const int ls = ((blockIdx.x & 127) << 8) + tid;
    float f[CIN];
    if constexpr (GATHER){
        const int s = ls >> 5;
        const int g = gidx[(size_t)b * LCOLS + ls];
        const float* px = xyz + (size_t)b * 3 * NPTS;
        const float cx = nx[b*3*NPOINT + s], cy = nx[b*3*NPOINT + NPOINT + s], cz = nx[b*3*NPOINT + 2*NPOINT + s];
        f[0] = sub_rn(px[g], cx); f[1] = sub_rn(px[NPTS+g], cy); f[2] = sub_rn(px[2*NPTS+g], cz);
        const u16x8* pr = (const u16x8*)(ptsT + ((size_t)b * NPTS + (size_t)g) * 64);
#pragma unroll
        for (int jj = 0; jj < 8; jj++){
            u16x8 v = pr[jj];
#pragma unroll
            for (int e = 0; e < 8; e++) f[3 + jj*8 + e] = bf2f(v[e]);
        }
    } else {
        const uint16_t* xp = xin + (size_t)b * CIN * LCOLS + ls;
#pragma unroll
        for (int c = 0; c < CIN; c++){
            float v = bf2f(xp[(size_t)c * LCOLS]);
            if constexpr (ACT) v = fmaxf(fmaf(sa[c], v, sa[CIN + c]), 0.0f);
            f[c] = v;
        }
    }
    uint16_t* op = xout + (size_t)b * COUT * LCOLS + ls;
    float* sbck = ssc + (blockIdx.x & (NBUCK-1)) * 256;
    for (int o0 = 0; o0 < COUT; o0 += 16){
        float acc[16];
#pragma unroll
        for (int j = 0; j < 16; j++) acc[j] = sb[o0 + j];
#pragma unroll
        for (int c = 0; c < CIN; c++){
            const float4* wr = (const float4*)(sw + c * COUT + o0);  // uniform -> LDS broadcast
            float4 w0_ = wr[0], w1_ = wr[1], w2_ = wr[2], w3_ = wr[3];
            const float fc = f[c];
            acc[0]  = fmaf(w0_.x, fc, acc[0]);  acc[1]  = fmaf(w0_.y, fc, acc[1]);
            acc[2]  = fmaf(w0_.z, fc, acc[2]);  acc[3]  = fmaf(w0_.w, fc, acc[3]);
            acc[4]  = fmaf(w1_.x, fc, acc[4]);  acc[5]  = fmaf(w1_.y, fc, acc[5]);
            acc[6]  = fmaf(w1_.z, fc, acc[6]);  acc[7]  = fmaf(w1_.w, fc, acc[7]);
            acc[8]  = fmaf(w2_.x, fc, acc[8]);  acc[9]  = fmaf(w2_.y, fc, acc[9]);
            acc[10] = fmaf(w2_.z, fc, acc[10]); acc[11] = fmaf(w2_.w, fc, acc[11]);
            acc[12] = fmaf(w3_.x, fc, acc[12]); acc[13] = fmaf(w3_.y, fc, acc[13]);
            acc[14] = fmaf(w3_.z, fc, acc[14]); acc[15] = fmaf(w3_.w, fc, acc[15]);
        }
        if constexpr (WRITE){
#pragma unroll
            for (int j = 0; j < 16; j++) op[(size_t)(o0 + j) * LCOLS] = f2bf(acc[j]);
        }
        // ---- block-level stats reduce on f32 accs ----
        __syncthreads();                       // protect sred reuse from previous group
#pragma unroll
        for (int k = 0; k < 16; k++) sred[k * 260 + tid] = acc[k];
        __syncthreads();
        const int ch = tid >> 4, seg = tid & 15;    // 16 ch x 16 segments of 16 cols
        float s = 0.f, ss = 0.f, mx = -1e30f, mn = 1e30f;
        const float4* rp = (const float4*)(sred + ch * 260 + seg * 16);
#pragma unroll
        for (int e = 0; e < 4; e++){
            float4 v = rp[e];
            s += v.x + v.y + v.z + v.w;
            ss = fmaf(v.x, v.x, ss); ss = fmaf(v.y, v.y, ss);
            ss = fmaf(v.z, v.z, ss); ss = fmaf(v.w, v.w, ss);
            if constexpr (MAXMIN){
                mx = fmaxf(mx, fmaxf(fmaxf(v.x, v.y), fmaxf(v.z, v.w)));
                mn = fminf(mn, fminf(fminf(v.x, v.y), fminf(v.z, v.w)));
            }
        }
        // 16 segs of one ch sit in consecutive lanes of one wave
#pragma unroll
        for (int off = 1; off < 16; off <<= 1){
            s += __shfl_xor(s, off); ss += __shfl_xor(ss, off);
            if constexpr (MAXMIN){ mx = fmaxf(mx, __shfl_xor(mx, off)); mn = fminf(mn, __shfl_xor(mn, off)); }
        }
        if (seg == 0){
            atomicAdd(&sbck[o0 + ch], s);
            atomicAdd(&sbck[128 + o0 + ch], ss);
            if constexpr (MAXMIN){
                atomicMax(&mmax[b * 128 + o0 + ch], fkey(mx));
                atomicMin(&mmin[b * 128 + o0 + ch], fkey(mn));
            }
        }
    }
}

// ---------- 4) BN params from bucketed sums -> per-channel affine a,c ----------
__global__ void params_kernel(const float* __restrict__ ssc, const float* __restrict__ g,
                              const float* __restrict__ beta, float* __restrict__ ac, int C){
    int o = threadIdx.x;
    if (o < C){
        float s = 0.f, ss = 0.f;
        for (int k = 0; k < NBUCK; k++){ s += ssc[k*256 + o]; ss += ssc[k*256 + 128 + o]; }
        const float inv = 1.0f / NTOT;
        float mean = s * inv;
        float var  = ss * inv - mean * mean;
        float a = g[o] / sqrtf(var + 1e-5f);
        ac[o] = a;
        ac[128 + o] = fmaf(-mean, a, beta[o]);
    }
}

// ---------- 5) finalize: out = relu(a * (a>=0 ? max : min) + c) per (b,ch) ----------
__global__ __launch_bounds__(64) void final_kernel(const float* __restrict__ ssc, const float* __restrict__ g2,
                                                   const float* __restrict__ be2, const unsigned* __restrict__ mmax,
                                                   const unsigned* __restrict__ mmin, float* __restrict__ out){
    const int t = blockIdx.x * 64 + threadIdx.x;   // 0..2047 : b*128+o
    const int o = t & 127;
    float s = 0.f, ss = 0.f;
    for (int k = 0; k < NBUCK; k++){ s += ssc[k*256 + o]; ss += ssc[k*256 + 128 + o]; }
    const float inv = 1.0f / NTOT;
    float mean = s * inv;
    float var  = ss * inv - mean * mean;
    float a = g2[o] / sqrtf(var + 1e-5f);
    float c = fmaf(-mean, a, be2[o]);
    unsigned k = (a >= 0.f) ? mmax[t] : mmin[t];   // relu(a*x+c) monotone in x, direction sign(a)
    float x = funkey(k);
    out[49152 + t] = fmaxf(fmaf(a, x, c), 0.0f);
}

extern "C" void kernel_launch(void* const* d_in, const int* in_sizes, int n_in,
                              void* d_out, int out_size, void* d_ws, size_t ws_size,
                              hipStream_t stream){
    const float* xyz = (const float*)d_in[0];
    const float* pts = (const float*)d_in[1];
    const float* w0  = (const float*)d_in[2];  const float* b0  = (const float*)d_in[3];
    const float* g0  = (const float*)d_in[4];  const float* be0 = (const float*)d_in[5];
    const float* w1  = (const float*)d_in[6];  const float* b1  = (const float*)d_in[7];
    const float* g1  = (const float*)d_in[8];  const float* be1 = (const float*)d_in[9];
    const float* w2  = (const float*)d_in[10]; const float* b2  = (const float*)d_in[11];
    const float* g2  = (const float*)d_in[12]; const float* be2 = (const float*)d_in[13];
    float* out = (float*)d_out;
    char* ws = (char*)d_ws;

    int*      fps_idx = (int*)(ws + OFF_FPS);
    int*      gidx    = (int*)(ws + OFF_GIDX);
    float*    ssc0    = (float*)(ws + OFF_SSC);            // 32*256
    float*    ssc1    = ssc0 + NBUCK*256;
    float*    ssc2    = ssc1 + NBUCK*256;
    float*    par0    = (float*)(ws + OFF_PAR);
    float*    par1    = par0 + 256;
    unsigned* mmax    = (unsigned*)(ws + OFF_MM);
    unsigned* mmin    = mmax + 2048;
    float*    wt0     = (float*)(ws + OFF_WT);
    float*    wt1     = wt0 + 67*64;
    float*    wt2     = wt1 + 64*64;
    uint16_t* t0      = (uint16_t*)(ws + OFF_T0);
    uint16_t* t1      = (uint16_t*)(ws + OFF_T1);
    uint16_t* ptsT    = (uint16_t*)(ws + OFF_PTST);

    hipMemsetAsync(ws + OFF_SSC, 0, 3 * NBUCK * 256 * 4, stream);
    hipMemsetAsync(ws + OFF_MM, 0x00, 8192, stream);          // key 0 < key(-inf)
    hipMemsetAsync(ws + OFF_MM + 8192, 0xFF, 8192, stream);   // key ~0 > key(+inf)

    fps_fused_kernel<<<536, 1024, 0, stream>>>(xyz, fps_idx, out, pts, ptsT,
                                               w0, w1, w2, wt0, wt1, wt2);
    ballquery_kernel<<<4096, 256, 0, stream>>>(xyz, fps_idx, gidx);

    mm_kernel<67, 64, false, true, true, false><<<2048, 256, 0, stream>>>(
        nullptr, xyz, out, ptsT, gidx, wt0, b0, nullptr, t0, ssc0, nullptr, nullptr);
    params_kernel<<<1, 128, 0, stream>>>(ssc0, g0, be0, par0, 64);

    mm_kernel<64, 64, true, false, true, false><<<2048, 256, 0, stream>>>(
        t0, nullptr, nullptr, nullptr, nullptr, wt1, b1, par0, t1, ssc1, nullptr, nullptr);
    params_kernel<<<1, 128, 0, stream>>>(ssc1, g1, be1, par1, 64);

    mm_kernel<64, 128, true, false, false, true><<<2048, 256, 0, stream>>>(
        t1, nullptr, nullptr, nullptr, nullptr, wt2, b2, par1, nullptr, ssc2, mmax, mmin);
    final_kernel<<<32, 64, 0, stream>>>(ssc2, g2, be2, mmax, mmin, out);
}

// Round 8
// 1413.494 us; speedup vs baseline: 1.1761x; 1.0957x over previous
//
#include <hip/hip_runtime.h>
#include <stdint.h>
#include <limits.h>

// ---------- exact-rounding helpers (block FMA contraction; match numpy op order) ----------
__device__ inline float mul_rn(float a, float b){ float r; asm("v_mul_f32 %0, %1, %2" : "=v"(r) : "v"(a), "v"(b)); return r; }
__device__ inline float add_rn(float a, float b){ float r; asm("v_add_f32 %0, %1, %2" : "=v"(r) : "v"(a), "v"(b)); return r; }
__device__ inline float sub_rn(float a, float b){ float r; asm("v_sub_f32 %0, %1, %2" : "=v"(r) : "v"(a), "v"(b)); return r; }

typedef uint16_t u16x8 __attribute__((ext_vector_type(8)));
typedef float    f32x2 __attribute__((ext_vector_type(2)));

// packed 2xf32 ops (VOP3P, IEEE RNE per element — bit-identical to scalar v_add/v_mul)
__device__ inline f32x2 pk_add2(f32x2 a, f32x2 b){ f32x2 r; asm("v_pk_add_f32 %0, %1, %2" : "=v"(r) : "v"(a), "v"(b)); return r; }
__device__ inline f32x2 pk_mul2(f32x2 a, f32x2 b){ f32x2 r; asm("v_pk_mul_f32 %0, %1, %2" : "=v"(r) : "v"(a), "v"(b)); return r; }

__device__ inline float bf2f(uint16_t u){ return __uint_as_float(((uint32_t)u) << 16); }
__device__ inline uint16_t f2bf(float f){
    uint32_t u = __float_as_uint(f);
    u += 0x7fffu + ((u >> 16) & 1u);   // RNE
    return (uint16_t)(u >> 16);
}
// monotonic uint key for float (total order): k(f) increasing in f
__device__ inline unsigned fkey(float f){
    unsigned u = __float_as_uint(f);
    return (u & 0x80000000u) ? ~u : (u | 0x80000000u);
}
__device__ inline float funkey(unsigned k){
    unsigned u = (k & 0x80000000u) ? (k ^ 0x80000000u) : ~k;
    return __uint_as_float(u);
}

// full-wave u32 max via DPP using the BUILTIN (compiler inserts the mandatory
// VALU->DPP hazard wait-states). Result valid in lane 63.
__device__ inline unsigned dpp_umax_wave(unsigned v){
    unsigned t;
    t = (unsigned)__builtin_amdgcn_update_dpp((int)v, (int)v, 0x111, 0xf, 0xf, false); v = v > t ? v : t; // row_shr:1
    t = (unsigned)__builtin_amdgcn_update_dpp((int)v, (int)v, 0x112, 0xf, 0xf, false); v = v > t ? v : t; // row_shr:2
    t = (unsigned)__builtin_amdgcn_update_dpp((int)v, (int)v, 0x114, 0xf, 0xf, false); v = v > t ? v : t; // row_shr:4
    t = (unsigned)__builtin_amdgcn_update_dpp((int)v, (int)v, 0x118, 0xf, 0xf, false); v = v > t ? v : t; // row_shr:8
    t = (unsigned)__builtin_amdgcn_update_dpp((int)v, (int)v, 0x142, 0xf, 0xf, false); v = v > t ? v : t; // row_bcast:15
    t = (unsigned)__builtin_amdgcn_update_dpp((int)v, (int)v, 0x143, 0xf, 0xf, false); v = v > t ? v : t; // row_bcast:31
    return v;
}

#define NPTS   8192
#define NBATCH 16
#define NPOINT 1024
#define NSAMP  32
#define LCOLS  32768          // NPOINT*NSAMP
#define NTOT   524288.0f      // 16*32768
#define NBUCK  32

// ---------- workspace layout (bytes) ----------
#define OFF_FPS   0u               // 16*1024*4 = 65536
#define OFF_GIDX  65536u           // 16*1024*32*4 = 2097152
#define OFF_SSC   2162688u         // 3 layers * 32 buckets * 256 f32 = 98304
#define OFF_PAR   2260992u         // 2 layers * 256 f32 = 2048
#define OFF_MM    2263040u         // mmax 2048 u32 ; mmin 2048 u32 = 16384
#define OFF_WT    2279424u         // 66304
#define OFF_T0    4194304u         // 67108864
#define OFF_T1    71303168u        // 67108864
#define OFF_PTST  138412032u       // 16777216 (end 155189248)

// ---------- 1) FUSED (256 thr/block): fps (0..15) + pts transpose (16..2063) + prep (2064..2095) ----------
__global__ __launch_bounds__(256) void fps_fused_kernel(const float* __restrict__ xyz,
        int* __restrict__ fps_idx, float* __restrict__ out_xyz,
        const float* __restrict__ pts, uint16_t* __restrict__ ptsT,
        const float* __restrict__ w0, const float* __restrict__ w1, const float* __restrict__ w2,
        float* __restrict__ wt0, float* __restrict__ wt1, float* __restrict__ wt2){
    __shared__ __align__(16) float smem[25616];   // sxyz 24576 + wslots 16 + sidx 1024
    const int bid = blockIdx.x, tid = threadIdx.x;

    if (bid >= 2064){                      // ---- prep path: wt[c][o] transposes ----
        int t = (bid - 2064) * 256 + tid;  // 0..8191
        if (t < 64*67){ int o = t / 67, c = t % 67; wt0[c*64 + o] = w0[t]; }
        if (t < 64*64){ int o = t >> 6, c = t & 63; wt1[c*64 + o] = w1[t]; }
        if (t < 128*64){ int o = t >> 6, c = t & 63; wt2[c*128 + o] = w2[t]; }
        return;
    }
    if (bid >= 16){                        // ---- transpose path: (B,64,N)f32 -> (B,N,64)bf16 ----
        float (*tile)[65] = (float(*)[65])smem;
        const int tb = bid - 16;
        const int bt = tb >> 7, n0 = (tb & 127) << 6;
        const int tn = tid & 63, tg = tid >> 6;
        const float* src = pts + (size_t)bt * 64 * NPTS + n0;
#pragma unroll
        for (int i = 0; i < 16; i++){ int c = tg*16 + i; tile[c][tn] = src[(size_t)c * NPTS + tn]; }
        __syncthreads();
        uint16_t* dst = ptsT + ((size_t)bt * NPTS + n0) * 64;
#pragma unroll
        for (int i = 0; i < 16; i++){ int n = tg*16 + i; dst[(size_t)n * 64 + tn] = f2bf(tile[tn][n]); }
        return;
    }

    // ---- fps path: 256 threads (4 waves = 1/SIMD), 32 points/thread ----
    float* sxyz = smem;                                                 // [8192*3] interleaved
    unsigned long long* wslots = (unsigned long long*)(smem + 24576);   // [2][4]
    int* sidx = (int*)(smem + 24592);                                   // [1024]
    const int b = bid;
    const float* px = xyz + (size_t)b * 3 * NPTS;
    for (int i0 = tid * 4; i0 < NPTS; i0 += 1024){
        float4 vx = *(const float4*)(px + i0);
        float4 vy = *(const float4*)(px + NPTS + i0);
        float4 vz = *(const float4*)(px + 2*NPTS + i0);
        float4* d = (float4*)(sxyz + 3*i0);
        d[0] = float4{vx.x, vy.x, vz.x, vx.y};
        d[1] = float4{vy.y, vz.y, vx.z, vy.z};
        d[2] = float4{vz.z, vx.w, vy.w, vz.w};
    }
    __syncthreads();

    // 32 contiguous points per thread from interleaved LDS: 24 x b128
    const int p0 = tid << 5;
    const float4* rp = (const float4*)(sxyz + 3*p0);
    f32x2 X2[16], Y2[16], Z2[16], M2[16];
#define UNPACK(k, A, B, C) \
    X2[2*(k)]   = f32x2{A.x, A.w}; Y2[2*(k)]   = f32x2{A.y, B.x}; Z2[2*(k)]   = f32x2{A.z, B.y}; \
    X2[2*(k)+1] = f32x2{B.z, C.y}; Y2[2*(k)+1] = f32x2{B.w, C.z}; Z2[2*(k)+1] = f32x2{C.x, C.w};
    {
        float4 q0=rp[0],q1=rp[1],q2=rp[2],q3=rp[3],q4=rp[4],q5=rp[5],q6=rp[6],q7=rp[7];
        float4 q8=rp[8],q9=rp[9],q10=rp[10],q11=rp[11],q12=rp[12],q13=rp[13],q14=rp[14],q15=rp[15];
        float4 q16=rp[16],q17=rp[17],q18=rp[18],q19=rp[19],q20=rp[20],q21=rp[21],q22=rp[22],q23=rp[23];
        UNPACK(0,q0,q1,q2)   UNPACK(1,q3,q4,q5)   UNPACK(2,q6,q7,q8)   UNPACK(3,q9,q10,q11)
        UNPACK(4,q12,q13,q14) UNPACK(5,q15,q16,q17) UNPACK(6,q18,q19,q20) UNPACK(7,q21,q22,q23)
    }
#undef UNPACK
#pragma unroll
    for (int j = 0; j < 16; j++) M2[j] = f32x2{1e10f, 1e10f};
    const unsigned base = ~(unsigned)p0;          // ~(p0+j) == base - j

    int cur = 0;
    float cx = sxyz[0], cy = sxyz[1], cz = sxyz[2];
    for (int t = 0; t < NPOINT; t++){
        if (tid == 0) sidx[t] = cur;               // record this iteration's centroid
        const f32x2 ncx = f32x2{-cx, -cx}, ncy = f32x2{-cy, -cy}, ncz = f32x2{-cz, -cz};
#pragma unroll
        for (int j = 0; j < 16; j++){
            f32x2 dx = pk_add2(X2[j], ncx);
            f32x2 dy = pk_add2(Y2[j], ncy);
            f32x2 dz = pk_add2(Z2[j], ncz);
            f32x2 d2 = pk_add2(pk_add2(pk_mul2(dx,dx), pk_mul2(dy,dy)), pk_mul2(dz,dz));
            M2[j].x = fminf(M2[j].x, d2.x);
            M2[j].y = fminf(M2[j].y, d2.y);
        }
        // thread-local max over 32 values
        float tv[16];
#pragma unroll
        for (int j = 0; j < 16; j++) tv[j] = fmaxf(M2[j].x, M2[j].y);
        float m0 = fmaxf(fmaxf(fmaxf(tv[0],tv[1]),fmaxf(tv[2],tv[3])), fmaxf(fmaxf(tv[4],tv[5]),fmaxf(tv[6],tv[7])));
        float m1 = fmaxf(fmaxf(fmaxf(tv[8],tv[9]),fmaxf(tv[10],tv[11])), fmaxf(fmaxf(tv[12],tv[13]),fmaxf(tv[14],tv[15])));
        const float mt = fmaxf(m0, m1);
        // smallest owned position with M==mt (descending scan, inline-const selects)
        unsigned jpos = 0;
#pragma unroll
        for (int j = 15; j >= 0; j--){
            if (M2[j].y == mt) jpos = 2*j + 1;
            if (M2[j].x == mt) jpos = 2*j;
        }
        const unsigned lo = base - jpos;           // == ~(p0 + jpos)
        const unsigned mtu = __float_as_uint(mt);  // d2>=0 -> uint order == float order
        unsigned vm = dpp_umax_wave(mtu);
        const unsigned wvu = __builtin_amdgcn_readlane(vm, 63);
        unsigned long long cand = __ballot(mtu == wvu);
        const int fl = __ffsll((long long)cand) - 1;        // lowest lane = smallest p
        const unsigned wlo = __builtin_amdgcn_readlane(lo, fl);
        if ((tid & 63) == 0)
            wslots[(t & 1) * 4 + (tid >> 6)] = (((unsigned long long)wvu) << 32) | wlo;
        __syncthreads();                            // the ONLY barrier per iter
        const ulonglong2* sp = (const ulonglong2*)(wslots + (t & 1) * 4);
        ulonglong2 ka = sp[0], kb = sp[1];          // 2 uniform b128 reads (broadcast)
        unsigned long long ma = (ka.y > ka.x) ? ka.y : ka.x;
        unsigned long long mb = (kb.y > kb.x) ? kb.y : kb.x;
        unsigned long long win = (mb > ma) ? mb : ma;
        cur = (int)(~((unsigned)win));
        cx = sxyz[3*cur]; cy = sxyz[3*cur+1]; cz = sxyz[3*cur+2];
    }
    __syncthreads();
    // output phase: 4 per thread
#pragma unroll
    for (int q = 0; q < 4; q++){
        const int i = (q << 8) + tid;
        const int idx = sidx[i];
        fps_idx[b * NPOINT + i] = idx;
        float* oxp = out_xyz + b * 3 * NPOINT;
        oxp[i]            = sxyz[3*idx];
        oxp[NPOINT + i]   = sxyz[3*idx+1];
        oxp[2*NPOINT + i] = sxyz[3*idx+2];
    }
}

// ---------- 2) ball query: one wave per (b,s) ----------
__global__ __launch_bounds__(256) void ballquery_kernel(const float* __restrict__ xyz,
                                                        const int* __restrict__ fps_idx, int* __restrict__ gidx){
    const int w = (blockIdx.x << 2) + (threadIdx.x >> 6);
    const int lane = threadIdx.x & 63;
    const int b = w >> 10, s = w & 1023;
    const float* px = xyz + (size_t)b * 3 * NPTS;
    const int ci = fps_idx[b * NPOINT + s];
    const float cx = px[ci], cy = px[NPTS+ci], cz = px[2*NPTS+ci];
    int* gout = gidx + (size_t)b * LCOLS + s * NSAMP;
    int have = 0, first_p = 0; bool got = false;
    for (int c0 = 0; c0 < NPTS; c0 += 64){
        int p = c0 + lane;
        float dx = sub_rn(px[p], cx), dy = sub_rn(px[NPTS+p], cy), dz = sub_rn(px[2*NPTS+p], cz);
        float d2 = add_rn(add_rn(mul_rn(dx,dx), mul_rn(dy,dy)), mul_rn(dz,dz));
        bool in = (d2 <= 0.01f);
        unsigned long long m = __ballot(in);
        if (m && !got){ first_p = c0 + __ffsll(m) - 1; got = true; }
        if (in){
            int pos = have + __popcll(m & ((1ull << lane) - 1ull));
            if (pos < NSAMP) gout[pos] = p;
        }
        have += __popcll(m);
        if (have >= NSAMP) break;
    }
    for (int pos = have + lane; pos < NSAMP; pos += 64) gout[pos] = first_p;
}

// ---------- 3) fused conv+BN-stats kernel ----------
template<int CIN, int COUT, bool ACT, bool GATHER, bool WRITE, bool MAXMIN>
__global__ __launch_bounds__(256) void mm_kernel(const uint16_t* __restrict__ xin,
        const float* __restrict__ xyz, const float* __restrict__ nx,
        const uint16_t* __restrict__ ptsT, const int* __restrict__ gidx,
        const float* __restrict__ wt, const float* __restrict__ bias, const float* __restrict__ ac,
        uint16_t* __restrict__ xout, float* __restrict__ ssc,
        unsigned* __restrict__ mmax, unsigned* __restrict__ mmin){
    __shared__ __align__(16) float sw[CIN * COUT];
    __shared__ float sb[COUT];
    __shared__ float sa[ACT ? 2*CIN : 1];
    __shared__ __align__(16) float sred[16 * 260];
    const int tid = threadIdx.x;
    for (int i = tid; i < CIN * COUT; i += 256) sw[i] = wt[i];
    if (tid < COUT) sb[tid] = bias[tid];
    if constexpr (ACT){ if (tid < CIN){ sa[tid] = ac[tid]; sa[CIN + tid] = ac[128 + tid]; } }
    __syncthreads();
    const int b = blockIdx.x >> 7;
    const int ls = ((blockIdx.x & 127) << 8) + tid;
    float f[CIN];
    if constexpr (GATHER){
        const int s = ls >> 5;
        const int g = gidx[(size_t)b * LCOLS + ls];
        const float* px = xyz + (size_t)b * 3 * NPTS;
        const float cx = nx[b*3*NPOINT + s], cy = nx[b*3*NPOINT + NPOINT + s], cz = nx[b*3*NPOINT + 2*NPOINT + s];
        f[0] = sub_rn(px[g], cx); f[1] = sub_rn(px[NPTS+g], cy); f[2] = sub_rn(px[2*NPTS+g], cz);
        const u16x8* pr = (const u16x8*)(ptsT + ((size_t)b * NPTS + (size_t)g) * 64);
#pragma unroll
        for (int jj = 0; jj < 8; jj++){
            u16x8 v = pr[jj];
#pragma unroll
            for (int e = 0; e < 8; e++) f[3 + jj*8 + e] = bf2f(v[e]);
        }
    } else {
        const uint16_t* xp = xin + (size_t)b * CIN * LCOLS + ls;
#pragma unroll
        for (int c = 0; c < CIN; c++){
            float v = bf2f(xp[(size_t)c * LCOLS]);
            if constexpr (ACT) v = fmaxf(fmaf(sa[c], v, sa[CIN + c]), 0.0f);
            f[c] = v;
        }
    }
    uint16_t* op = xout + (size_t)b * COUT * LCOLS + ls;
    float* sbck = ssc + (blockIdx.x & (NBUCK-1)) * 256;
    for (int o0 = 0; o0 < COUT; o0 += 16){
        float acc[16];
#pragma unroll
        for (int j = 0; j < 16; j++) acc[j] = sb[o0 + j];
#pragma unroll
        for (int c = 0; c < CIN; c++){
            const float4* wr = (const float4*)(sw + c * COUT + o0);  // uniform -> LDS broadcast
            float4 w0_ = wr[0], w1_ = wr[1], w2_ = wr[2], w3_ = wr[3];
            const float fc = f[c];
            acc[0]  = fmaf(w0_.x, fc, acc[0]);  acc[1]  = fmaf(w0_.y, fc, acc[1]);
            acc[2]  = fmaf(w0_.z, fc, acc[2]);  acc[3]  = fmaf(w0_.w, fc, acc[3]);
            acc[4]  = fmaf(w1_.x, fc, acc[4]);  acc[5]  = fmaf(w1_.y, fc, acc[5]);
            acc[6]  = fmaf(w1_.z, fc, acc[6]);  acc[7]  = fmaf(w1_.w, fc, acc[7]);
            acc[8]  = fmaf(w2_.x, fc, acc[8]);  acc[9]  = fmaf(w2_.y, fc, acc[9]);
            acc[10] = fmaf(w2_.z, fc, acc[10]); acc[11] = fmaf(w2_.w, fc, acc[11]);
            acc[12] = fmaf(w3_.x, fc, acc[12]); acc[13] = fmaf(w3_.y, fc, acc[13]);
            acc[14] = fmaf(w3_.z, fc, acc[14]); acc[15] = fmaf(w3_.w, fc, acc[15]);
        }
        if constexpr (WRITE){
#pragma unroll
            for (int j = 0; j < 16; j++) op[(size_t)(o0 + j) * LCOLS] = f2bf(acc[j]);
        }
        // ---- block-level stats reduce on f32 accs ----
        __syncthreads();                       // protect sred reuse from previous group
#pragma unroll
        for (int k = 0; k < 16; k++) sred[k * 260 + tid] = acc[k];
        __syncthreads();
        const int ch = tid >> 4, seg = tid & 15;    // 16 ch x 16 segments of 16 cols
        float s = 0.f, ss = 0.f, mx = -1e30f, mn = 1e30f;
        const float4* rp = (const float4*)(sred + ch * 260 + seg * 16);
#pragma unroll
        for (int e = 0; e < 4; e++){
            float4 v = rp[e];
            s += v.x + v.y + v.z + v.w;
            ss = fmaf(v.x, v.x, ss); ss = fmaf(v.y, v.y, ss);
            ss = fmaf(v.z, v.z, ss); ss = fmaf(v.w, v.w, ss);
            if constexpr (MAXMIN){
                mx = fmaxf(mx, fmaxf(fmaxf(v.x, v.y), fmaxf(v.z, v.w)));
                mn = fminf(mn, fminf(fminf(v.x, v.y), fminf(v.z, v.w)));
            }
        }
        // 16 segs of one ch sit in consecutive lanes of one wave
#pragma unroll
        for (int off = 1; off < 16; off <<= 1){
            s += __shfl_xor(s, off); ss += __shfl_xor(ss, off);
            if constexpr (MAXMIN){ mx = fmaxf(mx, __shfl_xor(mx, off)); mn = fminf(mn, __shfl_xor(mn, off)); }
        }
        if (seg == 0){
            atomicAdd(&sbck[o0 + ch], s);
            atomicAdd(&sbck[128 + o0 + ch], ss);
            if constexpr (MAXMIN){
                atomicMax(&mmax[b * 128 + o0 + ch], fkey(mx));
                atomicMin(&mmin[b * 128 + o0 + ch], fkey(mn));
            }
        }
    }
}

// ---------- 4) BN params from bucketed sums -> per-channel affine a,c ----------
__global__ void params_kernel(const float* __restrict__ ssc, const float* __restrict__ g,
                              const float* __restrict__ beta, float* __restrict__ ac, int C){
    int o = threadIdx.x;
    if (o < C){
        float s = 0.f, ss = 0.f;
        for (int k = 0; k < NBUCK; k++){ s += ssc[k*256 + o]; ss += ssc[k*256 + 128 + o]; }
        const float inv = 1.0f / NTOT;
        float mean = s * inv;
        float var  = ss * inv - mean * mean;
        float a = g[o] / sqrtf(var + 1e-5f);
        ac[o] = a;
        ac[128 + o] = fmaf(-mean, a, beta[o]);
    }
}

// ---------- 5) finalize: out = relu(a * (a>=0 ? max : min) + c) per (b,ch) ----------
__global__ __launch_bounds__(64) void final_kernel(const float* __restrict__ ssc, const float* __restrict__ g2,
                                                   const float* __restrict__ be2, const unsigned* __restrict__ mmax,
                                                   const unsigned* __restrict__ mmin, float* __restrict__ out){
    const int t = blockIdx.x * 64 + threadIdx.x;   // 0..2047 : b*128+o
    const int o = t & 127;
    float s = 0.f, ss = 0.f;
    for (int k = 0; k < NBUCK; k++){ s += ssc[k*256 + o]; ss += ssc[k*256 + 128 + o]; }
    const float inv = 1.0f / NTOT;
    float mean = s * inv;
    float var  = ss * inv - mean * mean;
    float a = g2[o] / sqrtf(var + 1e-5f);
    float c = fmaf(-mean, a, be2[o]);
    unsigned k = (a >= 0.f) ? mmax[t] : mmin[t];   // relu(a*x+c) monotone in x, direction sign(a)
    float x = funkey(k);
    out[49152 + t] = fmaxf(fmaf(a, x, c), 0.0f);
}

extern "C" void kernel_launch(void* const* d_in, const int* in_sizes, int n_in,
                              void* d_out, int out_size, void* d_ws, size_t ws_size,
                              hipStream_t stream){
    const float* xyz = (const float*)d_in[0];
    const float* pts = (const float*)d_in[1];
    const float* w0  = (const float*)d_in[2];  const float* b0  = (const float*)d_in[3];
    const float* g0  = (const float*)d_in[4];  const float* be0 = (const float*)d_in[5];
    const float* w1  = (const float*)d_in[6];  const float* b1  = (const float*)d_in[7];
    const float* g1  = (const float*)d_in[8];  const float* be1 = (const float*)d_in[9];
    const float* w2  = (const float*)d_in[10]; const float* b2  = (const float*)d_in[11];
    const float* g2  = (const float*)d_in[12]; const float* be2 = (const float*)d_in[13];
    float* out = (float*)d_out;
    char* ws = (char*)d_ws;

    int*      fps_idx = (int*)(ws + OFF_FPS);
    int*      gidx    = (int*)(ws + OFF_GIDX);
    float*    ssc0    = (float*)(ws + OFF_SSC);            // 32*256
    float*    ssc1    = ssc0 + NBUCK*256;
    float*    ssc2    = ssc1 + NBUCK*256;
    float*    par0    = (float*)(ws + OFF_PAR);
    float*    par1    = par0 + 256;
    unsigned* mmax    = (unsigned*)(ws + OFF_MM);
    unsigned* mmin    = mmax + 2048;
    float*    wt0     = (float*)(ws + OFF_WT);
    float*    wt1     = wt0 + 67*64;
    float*    wt2     = wt1 + 64*64;
    uint16_t* t0      = (uint16_t*)(ws + OFF_T0);
    uint16_t* t1      = (uint16_t*)(ws + OFF_T1);
    uint16_t* ptsT    = (uint16_t*)(ws + OFF_PTST);

    hipMemsetAsync(ws + OFF_SSC, 0, 3 * NBUCK * 256 * 4, stream);
    hipMemsetAsync(ws + OFF_MM, 0x00, 8192, stream);          // key 0 < key(-inf)
    hipMemsetAsync(ws + OFF_MM + 8192, 0xFF, 8192, stream);   // key ~0 > key(+inf)

    fps_fused_kernel<<<2096, 256, 0, stream>>>(xyz, fps_idx, out, pts, ptsT,
                                               w0, w1, w2, wt0, wt1, wt2);
    ballquery_kernel<<<4096, 256, 0, stream>>>(xyz, fps_idx, gidx);

    mm_kernel<67, 64, false, true, true, false><<<2048, 256, 0, stream>>>(
        nullptr, xyz, out, ptsT, gidx, wt0, b0, nullptr, t0, ssc0, nullptr, nullptr);
    params_kernel<<<1, 128, 0, stream>>>(ssc0, g0, be0, par0, 64);

    mm_kernel<64, 64, true, false, true, false><<<2048, 256, 0, stream>>>(
        t0, nullptr, nullptr, nullptr, nullptr, wt1, b1, par0, t1, ssc1, nullptr, nullptr);
    params_kernel<<<1, 128, 0, stream>>>(ssc1, g1, be1, par1, 64);

    mm_kernel<64, 128, true, false, false, true><<<2048, 256, 0, stream>>>(
        t1, nullptr, nullptr, nullptr, nullptr, wt2, b2, par1, nullptr, ssc2, mmax, mmin);
    final_kernel<<<32, 64, 0, stream>>>(ssc2, g2, be2, mmax, mmin, out);
}